// Round 2
// baseline (425.414 us; speedup 1.0000x reference)
//
#include <hip/hip_runtime.h>

typedef short s16x8 __attribute__((ext_vector_type(8)));
typedef float f32x4 __attribute__((ext_vector_type(4)));

__device__ inline float bf2f(unsigned short u) {
    union { float f; unsigned int i; } x; x.i = ((unsigned int)u) << 16; return x.f;
}
__device__ inline unsigned short f2bf(float f) {
    union { float f; unsigned int i; } x; x.f = f;
    unsigned int r = x.i + 0x7fff + ((x.i >> 16) & 1);
    return (unsigned short)(r >> 16);
}

__device__ inline void gload_lds16(const unsigned short* g, unsigned short* l) {
    __builtin_amdgcn_global_load_lds(
        (const __attribute__((address_space(1))) unsigned int*)g,
        (__attribute__((address_space(3))) unsigned int*)l, 16, 0, 0);
}

// ---------------------------------------------------------------------------
// Detect input dtype. For fp32 data, even-indexed uint16 halves are low
// mantissa bits -> exponent field uniform (only ~5% in [117,129]). For bf16
// data they are real values -> ~99.9% in range. flag=1 means fp32 inputs.
// ---------------------------------------------------------------------------
__global__ void detect_dtype(const unsigned short* __restrict__ x16, int* flag) {
    __shared__ int s[256];
    int tid = threadIdx.x;
    int cnt = 0;
    for (int i = tid; i < 4096; i += 256) {
        unsigned short u = x16[2 * i];
        int e = (u >> 7) & 0xFF;
        if (e >= 117 && e <= 129) cnt++;
    }
    s[tid] = cnt;
    __syncthreads();
    for (int off = 128; off; off >>= 1) {
        if (tid < off) s[tid] += s[tid + off];
        __syncthreads();
    }
    if (tid == 0) *flag = (s[0] < 2048) ? 1 : 0;
}

// ---------------------------------------------------------------------------
// Convert x -> bf16 (copy if already bf16). n multiple of 8.
// ---------------------------------------------------------------------------
__global__ void convert_x(const void* __restrict__ in, unsigned short* __restrict__ out,
                          const int* __restrict__ flag, int n) {
    int mode = *flag;
    int i0 = (blockIdx.x * 256 + threadIdx.x) * 8;
    if (i0 >= n) return;
    if (mode) {
        const float* f = (const float*)in;
#pragma unroll
        for (int j = 0; j < 8; ++j) out[i0 + j] = f2bf(f[i0 + j]);
    } else {
        *(s16x8*)(out + i0) = *(const s16x8*)((const unsigned short*)in + i0);
    }
}

__global__ void cvt_bias(const void* __restrict__ in, float* __restrict__ out,
                         const int* __restrict__ flag, int n) {
    int i = blockIdx.x * 256 + threadIdx.x;
    if (i >= n) return;
    out[i] = (*flag) ? ((const float*)in)[i] : bf2f(((const unsigned short*)in)[i]);
}

// ---------------------------------------------------------------------------
// Transpose + convert: (R x C) src (fp32 or bf16) -> (C x R) bf16
// ---------------------------------------------------------------------------
__global__ void transpose_cvt(const void* __restrict__ in, unsigned short* __restrict__ out,
                              const int* __restrict__ flag, int R, int C) {
    __shared__ unsigned short t[64][72];
    int mode = *flag;
    int r0 = blockIdx.y * 64, c0 = blockIdx.x * 64;
    for (int i = threadIdx.x; i < 64 * 64; i += 256) {
        int r = i >> 6, c = i & 63;
        size_t idx = (size_t)(r0 + r) * C + (c0 + c);
        t[r][c] = mode ? f2bf(((const float*)in)[idx]) : ((const unsigned short*)in)[idx];
    }
    __syncthreads();
    for (int i = threadIdx.x; i < 64 * 64; i += 256) {
        int c = i >> 6, r = i & 63;
        out[(size_t)(c0 + c) * R + (r0 + r)] = t[r][c];
    }
}

// ---------------------------------------------------------------------------
// GEMM: C(MxN) = A(MxK) * BT^T + bias. A,BT bf16; bias fp32; out bf16 or f32
// (outf32flag non-null and *outf32flag -> fp32 store). 128x128 tile, BK=64.
// ---------------------------------------------------------------------------
__global__ __launch_bounds__(256) void gemm_bias_kernel(
    const unsigned short* __restrict__ A, const unsigned short* __restrict__ BT,
    const float* __restrict__ bias, void* __restrict__ Cout,
    int M, int N, int K, const int* __restrict__ outf32flag) {
    __shared__ unsigned short As[8 * 128 * 8];  // 16KB
    __shared__ unsigned short Bs[8 * 128 * 8];  // 16KB
    int tid = threadIdx.x;
    int lane = tid & 63, w = tid >> 6;
    int wr = w >> 1, wc = w & 1;
    int m0 = blockIdx.y * 128, n0 = blockIdx.x * 128;

    f32x4 z = {0.f, 0.f, 0.f, 0.f};
    f32x4 acc[4][4];
#pragma unroll
    for (int m = 0; m < 4; ++m)
#pragma unroll
        for (int n = 0; n < 4; ++n) acc[m][n] = z;

    for (int k0 = 0; k0 < K; k0 += 64) {
        __syncthreads();
#pragma unroll
        for (int i = 0; i < 4; ++i) {
            int c = (w * 4 + i) * 64 + lane;
            int g = c >> 7, row = c & 127;
            gload_lds16(A + (size_t)(m0 + row) * K + (k0 + g * 8),
                        As + (size_t)(w * 4 + i) * 512);
            gload_lds16(BT + (size_t)(n0 + row) * K + (k0 + g * 8),
                        Bs + (size_t)(w * 4 + i) * 512);
        }
        __syncthreads();
#pragma unroll
        for (int kk = 0; kk < 2; ++kk) {
            int g = kk * 4 + (lane >> 4);
            s16x8 af[4], bf[4];
#pragma unroll
            for (int m = 0; m < 4; ++m)
                af[m] = *(const s16x8*)(As + ((size_t)g * 128 + wr * 64 + m * 16 + (lane & 15)) * 8);
#pragma unroll
            for (int n = 0; n < 4; ++n)
                bf[n] = *(const s16x8*)(Bs + ((size_t)g * 128 + wc * 64 + n * 16 + (lane & 15)) * 8);
#pragma unroll
            for (int m = 0; m < 4; ++m)
#pragma unroll
                for (int n = 0; n < 4; ++n)
                    acc[m][n] = __builtin_amdgcn_mfma_f32_16x16x32_bf16(af[m], bf[n], acc[m][n], 0, 0, 0);
        }
    }

    bool f32out = (outf32flag != nullptr) && (*outf32flag != 0);
    int crow0 = m0 + wr * 64;
    int ccol0 = n0 + wc * 64;
#pragma unroll
    for (int n = 0; n < 4; ++n) {
        int col = ccol0 + n * 16 + (lane & 15);
        float bv = bias[col];
#pragma unroll
        for (int m = 0; m < 4; ++m) {
            int rbase = crow0 + m * 16 + (lane >> 4) * 4;
#pragma unroll
            for (int q = 0; q < 4; ++q) {
                float v = acc[m][n][q] + bv;
                if (f32out)
                    ((float*)Cout)[(size_t)(rbase + q) * N + col] = v;
                else
                    ((unsigned short*)Cout)[(size_t)(rbase + q) * N + col] = f2bf(v);
            }
        }
    }
}

// ---------------------------------------------------------------------------
// Flash attention. qkv (8192 rows = s*4+b, 3072) bf16: [Q | K | V].
// Block: one (b,h), 64 q-rows (4 waves x 16). KV tiles of 64.
// ---------------------------------------------------------------------------
__global__ __launch_bounds__(256) void attn_kernel(
    const unsigned short* __restrict__ qkv, unsigned short* __restrict__ O) {
    int bh = blockIdx.y;
    int b = bh >> 4, h = bh & 15;
    int q0 = blockIdx.x * 64;
    int tid = threadIdx.x, lane = tid & 63, w = tid >> 6;

    __shared__ unsigned short Ks[8 * 64 * 8];   // [g=d/8][s][8]
    __shared__ unsigned short Vs[8 * 64 * 8];   // VT blocks, xor-swizzled
    __shared__ unsigned short Ps[4][8 * 16 * 8];

    const size_t RS = 3072;

    int qrow = q0 + w * 16 + (lane & 15);
    const unsigned short* qp = qkv + ((size_t)qrow * 4 + b) * RS + h * 64 + (lane >> 4) * 8;
    s16x8 qf[2];
    qf[0] = *(const s16x8*)(qp);
    qf[1] = *(const s16x8*)(qp + 32);

    f32x4 z = {0.f, 0.f, 0.f, 0.f};
    f32x4 oacc[4];
#pragma unroll
    for (int nt = 0; nt < 4; ++nt) oacc[nt] = z;
    float mrow[4], lrow[4];
#pragma unroll
    for (int r = 0; r < 4; ++r) { mrow[r] = -1e30f; lrow[r] = 0.f; }

    int vs_s = tid & 63;
    int vs_d0 = (tid >> 6) * 16;
    unsigned short* pw = &Ps[w][0];

    for (int k0 = 0; k0 < 2048; k0 += 64) {
        __syncthreads();
        {
            const unsigned short* ksrc = qkv + ((size_t)(k0 + lane) * 4 + b) * RS + 1024 + h * 64;
            gload_lds16(ksrc + w * 8, Ks + (size_t)w * 512);
            gload_lds16(ksrc + (w + 4) * 8, Ks + (size_t)(w + 4) * 512);
        }
        {
            const unsigned short* vsrc = qkv + ((size_t)(k0 + vs_s) * 4 + b) * RS + 2048 + h * 64 + vs_d0;
            s16x8 v0 = *(const s16x8*)(vsrc);
            s16x8 v1 = *(const s16x8*)(vsrc + 8);
            int gk = vs_s >> 3, slot = vs_s & 7;
#pragma unroll
            for (int j = 0; j < 8; ++j) {
                int dd0 = vs_d0 + j;
                Vs[(gk * 64 + (dd0 ^ (gk & 7))) * 8 + slot] = (unsigned short)v0[j];
                int dd1 = vs_d0 + 8 + j;
                Vs[(gk * 64 + (dd1 ^ (gk & 7))) * 8 + slot] = (unsigned short)v1[j];
            }
        }
        __syncthreads();

        f32x4 sc[4];
#pragma unroll
        for (int ct = 0; ct < 4; ++ct) sc[ct] = z;
#pragma unroll
        for (int kk = 0; kk < 2; ++kk) {
            int g = kk * 4 + (lane >> 4);
#pragma unroll
            for (int ct = 0; ct < 4; ++ct) {
                s16x8 kf = *(const s16x8*)(Ks + ((size_t)g * 64 + ct * 16 + (lane & 15)) * 8);
                sc[ct] = __builtin_amdgcn_mfma_f32_16x16x32_bf16(qf[kk], kf, sc[ct], 0, 0, 0);
            }
        }

        float pm[4][4];
#pragma unroll
        for (int reg = 0; reg < 4; ++reg) {
            float rmax = fmaxf(fmaxf(sc[0][reg], sc[1][reg]), fmaxf(sc[2][reg], sc[3][reg]));
            rmax *= 0.125f;
#pragma unroll
            for (int off = 1; off < 16; off <<= 1)
                rmax = fmaxf(rmax, __shfl_xor(rmax, off));
            float mnew = fmaxf(mrow[reg], rmax);
            float alpha = __expf(mrow[reg] - mnew);
            float rsum = 0.f;
#pragma unroll
            for (int ct = 0; ct < 4; ++ct) {
                float p = __expf(sc[ct][reg] * 0.125f - mnew);
                pm[ct][reg] = p;
                rsum += p;
            }
#pragma unroll
            for (int off = 1; off < 16; off <<= 1)
                rsum += __shfl_xor(rsum, off);
            lrow[reg] = lrow[reg] * alpha + rsum;
            mrow[reg] = mnew;
#pragma unroll
            for (int nt = 0; nt < 4; ++nt) oacc[nt][reg] *= alpha;
        }

#pragma unroll
        for (int ct = 0; ct < 4; ++ct) {
            int g = ct * 2 + ((lane & 15) >> 3);
            int slot = lane & 7;
#pragma unroll
            for (int reg = 0; reg < 4; ++reg) {
                int r = (lane >> 4) * 4 + reg;
                pw[(g * 16 + r) * 8 + slot] = f2bf(pm[ct][reg]);
            }
        }
        __syncthreads();

#pragma unroll
        for (int kk = 0; kk < 2; ++kk) {
            int gk = kk * 4 + (lane >> 4);
            s16x8 pa = *(const s16x8*)(pw + ((size_t)gk * 16 + (lane & 15)) * 8);
#pragma unroll
            for (int nt = 0; nt < 4; ++nt) {
                int dd = nt * 16 + (lane & 15);
                s16x8 vf = *(const s16x8*)(Vs + (size_t)(gk * 64 + (dd ^ (gk & 7))) * 8);
                oacc[nt] = __builtin_amdgcn_mfma_f32_16x16x32_bf16(pa, vf, oacc[nt], 0, 0, 0);
            }
        }
    }

#pragma unroll
    for (int reg = 0; reg < 4; ++reg) {
        int s = q0 + w * 16 + (lane >> 4) * 4 + reg;
        float rl = 1.f / lrow[reg];
        size_t orow = ((size_t)s * 4 + b) * 1024 + h * 64;
#pragma unroll
        for (int nt = 0; nt < 4; ++nt) {
            O[orow + nt * 16 + (lane & 15)] = f2bf(oacc[nt][reg] * rl);
        }
    }
}

// ---------------------------------------------------------------------------
extern "C" void kernel_launch(void* const* d_in, const int* in_sizes, int n_in,
                              void* d_out, int out_size, void* d_ws, size_t ws_size,
                              hipStream_t stream) {
    const void* x    = d_in[0];  // (2048,4,1024)
    const void* Wqkv = d_in[1];  // (1024,3072)
    const void* bqkv = d_in[2];  // (3072)
    const void* Wout = d_in[3];  // (1024,1024)
    const void* bout = d_in[4];  // (1024)

    char* ws = (char*)d_ws;
    unsigned short* qkv   = (unsigned short*)(ws);              // 48MB
    unsigned short* Obuf  = (unsigned short*)(ws + 50331648);   // 16MB
    unsigned short* WqkvT = (unsigned short*)(ws + 67108864);   // 6MB
    unsigned short* WoutT = (unsigned short*)(ws + 73400320);   // 2MB
    unsigned short* xb    = (unsigned short*)(ws + 75497472);   // 16MB
    float*          bq_f  = (float*)(ws + 92274688);            // 12KB
    float*          bo_f  = (float*)(ws + 92286976);            // 4KB
    int*            flag  = (int*)(ws + 92291072);

    detect_dtype<<<1, 256, 0, stream>>>((const unsigned short*)x, flag);
    convert_x<<<4096, 256, 0, stream>>>(x, xb, flag, 8388608);
    cvt_bias<<<12, 256, 0, stream>>>(bqkv, bq_f, flag, 3072);
    cvt_bias<<<4, 256, 0, stream>>>(bout, bo_f, flag, 1024);
    transpose_cvt<<<dim3(48, 16), 256, 0, stream>>>(Wqkv, WqkvT, flag, 1024, 3072);
    transpose_cvt<<<dim3(16, 16), 256, 0, stream>>>(Wout, WoutT, flag, 1024, 1024);

    gemm_bias_kernel<<<dim3(24, 64), 256, 0, stream>>>(xb, WqkvT, bq_f, qkv, 8192, 3072, 1024, nullptr);
    attn_kernel<<<dim3(32, 64), 256, 0, stream>>>(qkv, Obuf);
    gemm_bias_kernel<<<dim3(8, 64), 256, 0, stream>>>(Obuf, WoutT, bo_f, d_out, 8192, 1024, 1024, flag);
}

// Round 3
// 343.551 us; speedup vs baseline: 1.2383x; 1.2383x over previous
//
#include <hip/hip_runtime.h>

typedef short s16x8 __attribute__((ext_vector_type(8)));
typedef float f32x4 __attribute__((ext_vector_type(4)));
typedef unsigned int u32x2 __attribute__((ext_vector_type(2)));

__device__ inline float bf2f(unsigned short u) {
    union { float f; unsigned int i; } x; x.i = ((unsigned int)u) << 16; return x.f;
}
__device__ inline unsigned short f2bf(float f) {
    union { float f; unsigned int i; } x; x.f = f;
    unsigned int r = x.i + 0x7fff + ((x.i >> 16) & 1);
    return (unsigned short)(r >> 16);
}

__device__ inline void gload_lds16(const unsigned short* g, unsigned short* l) {
    __builtin_amdgcn_global_load_lds(
        (const __attribute__((address_space(1))) unsigned int*)g,
        (__attribute__((address_space(3))) unsigned int*)l, 16, 0, 0);
}

// ---------------------------------------------------------------------------
// Input dtype probe: fp32 low-halves have ~uniform exponent bits; bf16 data
// concentrates in [117,129]. flag=1 -> inputs are fp32.
// ---------------------------------------------------------------------------
__global__ void detect_dtype(const unsigned short* __restrict__ x16, int* flag) {
    __shared__ int s[256];
    int tid = threadIdx.x;
    int cnt = 0;
    for (int i = tid; i < 4096; i += 256) {
        unsigned short u = x16[2 * i];
        int e = (u >> 7) & 0xFF;
        if (e >= 117 && e <= 129) cnt++;
    }
    s[tid] = cnt;
    __syncthreads();
    for (int off = 128; off; off >>= 1) {
        if (tid < off) s[tid] += s[tid + off];
        __syncthreads();
    }
    if (tid == 0) *flag = (s[0] < 2048) ? 1 : 0;
}

__global__ void convert_x(const void* __restrict__ in, unsigned short* __restrict__ out,
                          const int* __restrict__ flag, int n) {
    int mode = *flag;
    int i0 = (blockIdx.x * 256 + threadIdx.x) * 8;
    if (i0 >= n) return;
    if (mode) {
        const float* f = (const float*)in;
#pragma unroll
        for (int j = 0; j < 8; ++j) out[i0 + j] = f2bf(f[i0 + j]);
    } else {
        *(s16x8*)(out + i0) = *(const s16x8*)((const unsigned short*)in + i0);
    }
}

__global__ void cvt_bias(const void* __restrict__ in, float* __restrict__ out,
                         const int* __restrict__ flag, int n) {
    int i = blockIdx.x * 256 + threadIdx.x;
    if (i >= n) return;
    out[i] = (*flag) ? ((const float*)in)[i] : bf2f(((const unsigned short*)in)[i]);
}

// ---------------------------------------------------------------------------
// Transpose + convert weights: (R x C) fp32/bf16 -> (C x R) bf16
// ---------------------------------------------------------------------------
__global__ void transpose_cvt(const void* __restrict__ in, unsigned short* __restrict__ out,
                              const int* __restrict__ flag, int R, int C) {
    __shared__ unsigned short t[64][72];
    int mode = *flag;
    int r0 = blockIdx.y * 64, c0 = blockIdx.x * 64;
    for (int i = threadIdx.x; i < 64 * 64; i += 256) {
        int r = i >> 6, c = i & 63;
        size_t idx = (size_t)(r0 + r) * C + (c0 + c);
        t[r][c] = mode ? f2bf(((const float*)in)[idx]) : ((const unsigned short*)in)[idx];
    }
    __syncthreads();
    for (int i = threadIdx.x; i < 64 * 64; i += 256) {
        int c = i >> 6, r = i & 63;
        out[(size_t)(c0 + c) * R + (r0 + r)] = t[r][c];
    }
}

// ---------------------------------------------------------------------------
// V transpose: qkv V region -> Vt[bh][64 d][2048 k] (bf16)
// ---------------------------------------------------------------------------
__global__ __launch_bounds__(256) void transpose_v(
    const unsigned short* __restrict__ qkv, unsigned short* __restrict__ Vt) {
    __shared__ unsigned short t[64][72];
    int bh = blockIdx.y; int b = bh >> 4, h = bh & 15;
    int k0 = blockIdx.x * 64;
    int tid = threadIdx.x;
    int kr = tid >> 2, db = (tid & 3) * 16;
    const unsigned short* src = qkv + ((size_t)(k0 + kr) * 4 + b) * 3072 + 2048 + h * 64 + db;
    *(s16x8*)&t[kr][db] = *(const s16x8*)src;
    *(s16x8*)&t[kr][db + 8] = *(const s16x8*)(src + 8);
    __syncthreads();
    int d = tid >> 2, kb = (tid & 3) * 16;
    unsigned short* dst = Vt + (size_t)bh * 131072 + (size_t)d * 2048 + k0 + kb;
    s16x8 a, c;
#pragma unroll
    for (int j = 0; j < 8; ++j) a[j] = t[kb + j][d];
#pragma unroll
    for (int j = 0; j < 8; ++j) c[j] = t[kb + 8 + j][d];
    *(s16x8*)dst = a;
    *(s16x8*)(dst + 8) = c;
}

// ---------------------------------------------------------------------------
// GEMM: C = A * BT^T + bias. cols < qcols get *0.125 (exact in bf16).
// 128x128 tile, BK=64, 4 waves.
// ---------------------------------------------------------------------------
__global__ __launch_bounds__(256) void gemm_bias_kernel(
    const unsigned short* __restrict__ A, const unsigned short* __restrict__ BT,
    const float* __restrict__ bias, void* __restrict__ Cout,
    int M, int N, int K, int qcols, const int* __restrict__ outf32flag) {
    __shared__ unsigned short As[8 * 128 * 8];
    __shared__ unsigned short Bs[8 * 128 * 8];
    int tid = threadIdx.x;
    int lane = tid & 63, w = tid >> 6;
    int wr = w >> 1, wc = w & 1;
    int m0 = blockIdx.y * 128, n0 = blockIdx.x * 128;

    f32x4 z = {0.f, 0.f, 0.f, 0.f};
    f32x4 acc[4][4];
#pragma unroll
    for (int m = 0; m < 4; ++m)
#pragma unroll
        for (int n = 0; n < 4; ++n) acc[m][n] = z;

    for (int k0 = 0; k0 < K; k0 += 64) {
        __syncthreads();
#pragma unroll
        for (int i = 0; i < 4; ++i) {
            int c = (w * 4 + i) * 64 + lane;
            int gg = c >> 7, row = c & 127;
            gload_lds16(A + (size_t)(m0 + row) * K + (k0 + gg * 8),
                        As + (size_t)(w * 4 + i) * 512);
            gload_lds16(BT + (size_t)(n0 + row) * K + (k0 + gg * 8),
                        Bs + (size_t)(w * 4 + i) * 512);
        }
        __syncthreads();
#pragma unroll
        for (int kk = 0; kk < 2; ++kk) {
            int gg = kk * 4 + (lane >> 4);
            s16x8 af[4], bf[4];
#pragma unroll
            for (int m = 0; m < 4; ++m)
                af[m] = *(const s16x8*)(As + ((size_t)gg * 128 + wr * 64 + m * 16 + (lane & 15)) * 8);
#pragma unroll
            for (int n = 0; n < 4; ++n)
                bf[n] = *(const s16x8*)(Bs + ((size_t)gg * 128 + wc * 64 + n * 16 + (lane & 15)) * 8);
#pragma unroll
            for (int m = 0; m < 4; ++m)
#pragma unroll
                for (int n = 0; n < 4; ++n)
                    acc[m][n] = __builtin_amdgcn_mfma_f32_16x16x32_bf16(af[m], bf[n], acc[m][n], 0, 0, 0);
        }
    }

    bool f32out = (outf32flag != nullptr) && (*outf32flag != 0);
    int crow0 = m0 + wr * 64;
    int ccol0 = n0 + wc * 64;
#pragma unroll
    for (int n = 0; n < 4; ++n) {
        int col = ccol0 + n * 16 + (lane & 15);
        float bv = bias[col];
        float qs = (col < qcols) ? 0.125f : 1.0f;
#pragma unroll
        for (int m = 0; m < 4; ++m) {
            int rbase = crow0 + m * 16 + (lane >> 4) * 4;
#pragma unroll
            for (int q = 0; q < 4; ++q) {
                float v = (acc[m][n][q] + bv) * qs;
                if (f32out)
                    ((float*)Cout)[(size_t)(rbase + q) * N + col] = v;
                else
                    ((unsigned short*)Cout)[(size_t)(rbase + q) * N + col] = f2bf(v);
            }
        }
    }
}

// ---------------------------------------------------------------------------
// Flash attention, swapped operands. qkv rows (s*4+b, 3072): [Q/8 | K | V].
// Block: one (b,h), 128 q-rows = 4 waves x 2 subtiles x 16. KV tiles of 64.
// S^T = mfma(K, Q); each lane owns one q-row per subtile (col = lane&15).
// O^T = mfma(V^T, P) with per-wave P bounce in LDS (no barrier).
// ---------------------------------------------------------------------------
__global__ __launch_bounds__(256) void attn_kernel(
    const unsigned short* __restrict__ qkv, const unsigned short* __restrict__ Vt,
    unsigned short* __restrict__ O) {
    int bh = blockIdx.y;
    int b = bh >> 4, h = bh & 15;
    int q0 = blockIdx.x * 128;
    int tid = threadIdx.x, lane = tid & 63, w = tid >> 6;
    int g = lane >> 4, qh = lane & 15;

    __shared__ unsigned short Ks[8 * 64 * 8];     // [gd=d/8][k][8]   8KB
    __shared__ unsigned short Vs[64 * 64];        // V^T [d][blk-swz] 8KB
    __shared__ unsigned short Pb[4][2][16 * 64];  // per-wave/qs P    16KB

    // Q fragments (Q pre-scaled by 1/8 in GEMM1)
    s16x8 qf[2][2];
#pragma unroll
    for (int qs = 0; qs < 2; ++qs) {
        int qrow = q0 + w * 32 + qs * 16 + qh;
        const unsigned short* qp = qkv + ((size_t)qrow * 4 + b) * 3072 + h * 64 + g * 8;
        qf[qs][0] = *(const s16x8*)qp;
        qf[qs][1] = *(const s16x8*)(qp + 32);
    }

    f32x4 z = {0.f, 0.f, 0.f, 0.f};
    f32x4 oacc[2][4];
#pragma unroll
    for (int qs = 0; qs < 2; ++qs)
#pragma unroll
        for (int dt = 0; dt < 4; ++dt) oacc[qs][dt] = z;
    float mrun[2] = {-1e30f, -1e30f};
    float lrun[2] = {0.f, 0.f};

    int vxor = (lane & 7) ^ (lane >> 3);  // src-block xor for V staging

    for (int k0 = 0; k0 < 2048; k0 += 64) {
        __syncthreads();
        // stage K tile: Ks[gd][k][e] = K[k0+k][gd*8+e]
        {
            const unsigned short* ksrc = qkv + ((size_t)(k0 + lane) * 4 + b) * 3072 + 1024 + h * 64;
            gload_lds16(ksrc + w * 8, Ks + (size_t)w * 512);
            gload_lds16(ksrc + (w + 4) * 8, Ks + (size_t)(w + 4) * 512);
        }
        // stage V^T tile with inverse-swizzled source (linear LDS dest):
        // Vs elem (d, blk, j) holds V^T[d][k0 + (blk^(d&7))*8 + j]
#pragma unroll
        for (int c = 0; c < 2; ++c) {
            int d = (c * 4 + w) * 8 + (lane >> 3);
            const unsigned short* vsrc = Vt + (size_t)bh * 131072 + (size_t)d * 2048 + k0 + vxor * 8;
            gload_lds16(vsrc, Vs + (size_t)(c * 4 + w) * 512);
        }
        __syncthreads();

        // ---- S^T[k][q] = K Q^T : sc[qs][ct], k = ct*16 + g*4 + reg, q = qh
        f32x4 sc[2][4];
#pragma unroll
        for (int qs = 0; qs < 2; ++qs)
#pragma unroll
            for (int ct = 0; ct < 4; ++ct) sc[qs][ct] = z;
#pragma unroll
        for (int kk = 0; kk < 2; ++kk)
#pragma unroll
            for (int ct = 0; ct < 4; ++ct) {
                s16x8 kf = *(const s16x8*)(Ks + ((size_t)(kk * 4 + g) * 64 + ct * 16 + qh) * 8);
                sc[0][ct] = __builtin_amdgcn_mfma_f32_16x16x32_bf16(kf, qf[0][kk], sc[0][ct], 0, 0, 0);
                sc[1][ct] = __builtin_amdgcn_mfma_f32_16x16x32_bf16(kf, qf[1][kk], sc[1][ct], 0, 0, 0);
            }

        // ---- online softmax per subtile (lane owns one q-row)
#pragma unroll
        for (int qs = 0; qs < 2; ++qs) {
            float tmax = sc[qs][0][0];
#pragma unroll
            for (int ct = 0; ct < 4; ++ct)
#pragma unroll
                for (int r = 0; r < 4; ++r) tmax = fmaxf(tmax, sc[qs][ct][r]);
            tmax = fmaxf(tmax, __shfl_xor(tmax, 16));
            tmax = fmaxf(tmax, __shfl_xor(tmax, 32));
            float mnew = fmaxf(mrun[qs], tmax);
            float alpha = __expf(mrun[qs] - mnew);
            mrun[qs] = mnew;
            float rsum = 0.f;
            unsigned short* pwq = &Pb[w][qs][0];
#pragma unroll
            for (int ct = 0; ct < 4; ++ct) {
                float p0 = __expf(sc[qs][ct][0] - mnew);
                float p1 = __expf(sc[qs][ct][1] - mnew);
                float p2 = __expf(sc[qs][ct][2] - mnew);
                float p3 = __expf(sc[qs][ct][3] - mnew);
                rsum += (p0 + p1) + (p2 + p3);
                u32x2 pv;
                pv[0] = (unsigned int)f2bf(p0) | ((unsigned int)f2bf(p1) << 16);
                pv[1] = (unsigned int)f2bf(p2) | ((unsigned int)f2bf(p3) << 16);
                int blk = ct * 2 + (g >> 1);
                int e = qh * 64 + ((blk ^ (qh & 7)) * 8) + (g & 1) * 4;
                *(u32x2*)(pwq + e) = pv;
            }
            rsum += __shfl_xor(rsum, 16);
            rsum += __shfl_xor(rsum, 32);
            lrun[qs] = lrun[qs] * alpha + rsum;
#pragma unroll
            for (int dt = 0; dt < 4; ++dt) oacc[qs][dt] *= alpha;
        }

        // P writes must complete before B-frag reads (same wave, cross-lane)
        asm volatile("s_waitcnt lgkmcnt(0)" ::: "memory");
        __builtin_amdgcn_sched_barrier(0);

        // ---- O^T += V^T P : A = V^T frag, B = P frag
#pragma unroll
        for (int kk2 = 0; kk2 < 2; ++kk2) {
            int blkr = ((kk2 * 4 + g) ^ (qh & 7)) * 8;
            s16x8 pb0 = *(const s16x8*)(&Pb[w][0][0] + qh * 64 + blkr);
            s16x8 pb1 = *(const s16x8*)(&Pb[w][1][0] + qh * 64 + blkr);
#pragma unroll
            for (int dt = 0; dt < 4; ++dt) {
                s16x8 vtf = *(const s16x8*)(Vs + (size_t)(dt * 16 + qh) * 64 + blkr);
                oacc[0][dt] = __builtin_amdgcn_mfma_f32_16x16x32_bf16(vtf, pb0, oacc[0][dt], 0, 0, 0);
                oacc[1][dt] = __builtin_amdgcn_mfma_f32_16x16x32_bf16(vtf, pb1, oacc[1][dt], 0, 0, 0);
            }
        }
    }

    // ---- epilogue: O[(s*4+b)*1024 + h*64 + d], d = dt*16 + g*4 + reg
#pragma unroll
    for (int qs = 0; qs < 2; ++qs) {
        float rl = 1.f / lrun[qs];
        int s = q0 + w * 32 + qs * 16 + qh;
        unsigned short* orow = O + ((size_t)s * 4 + b) * 1024 + h * 64;
#pragma unroll
        for (int dt = 0; dt < 4; ++dt) {
            u32x2 pv;
            pv[0] = (unsigned int)f2bf(oacc[qs][dt][0] * rl) |
                    ((unsigned int)f2bf(oacc[qs][dt][1] * rl) << 16);
            pv[1] = (unsigned int)f2bf(oacc[qs][dt][2] * rl) |
                    ((unsigned int)f2bf(oacc[qs][dt][3] * rl) << 16);
            *(u32x2*)(orow + dt * 16 + g * 4) = pv;
        }
    }
}

// ---------------------------------------------------------------------------
extern "C" void kernel_launch(void* const* d_in, const int* in_sizes, int n_in,
                              void* d_out, int out_size, void* d_ws, size_t ws_size,
                              hipStream_t stream) {
    const void* x    = d_in[0];
    const void* Wqkv = d_in[1];
    const void* bqkv = d_in[2];
    const void* Wout = d_in[3];
    const void* bout = d_in[4];

    char* ws = (char*)d_ws;
    unsigned short* qkv   = (unsigned short*)(ws);              // 48MB
    unsigned short* Obuf  = (unsigned short*)(ws + 50331648);   // 16MB
    unsigned short* WqkvT = (unsigned short*)(ws + 67108864);   // 6MB
    unsigned short* WoutT = (unsigned short*)(ws + 73400320);   // 2MB
    unsigned short* xb    = (unsigned short*)(ws + 75497472);   // 16MB (reused as Vt)
    unsigned short* Vtg   = xb;                                 // alias: xb dead after GEMM1
    float*          bq_f  = (float*)(ws + 92274688);
    float*          bo_f  = (float*)(ws + 92286976);
    int*            flag  = (int*)(ws + 92291072);

    detect_dtype<<<1, 256, 0, stream>>>((const unsigned short*)x, flag);
    convert_x<<<4096, 256, 0, stream>>>(x, xb, flag, 8388608);
    cvt_bias<<<12, 256, 0, stream>>>(bqkv, bq_f, flag, 3072);
    cvt_bias<<<4, 256, 0, stream>>>(bout, bo_f, flag, 1024);
    transpose_cvt<<<dim3(48, 16), 256, 0, stream>>>(Wqkv, WqkvT, flag, 1024, 3072);
    transpose_cvt<<<dim3(16, 16), 256, 0, stream>>>(Wout, WoutT, flag, 1024, 1024);

    gemm_bias_kernel<<<dim3(24, 64), 256, 0, stream>>>(xb, WqkvT, bq_f, qkv,
                                                       8192, 3072, 1024, 1024, nullptr);
    transpose_v<<<dim3(32, 64), 256, 0, stream>>>(qkv, Vtg);
    attn_kernel<<<dim3(16, 64), 256, 0, stream>>>(qkv, Vtg, Obuf);
    gemm_bias_kernel<<<dim3(8, 64), 256, 0, stream>>>(Obuf, WoutT, bo_f, d_out,
                                                      8192, 1024, 1024, 0, flag);
}